// Round 2
// baseline (1427.078 us; speedup 1.0000x reference)
//
#include <hip/hip_runtime.h>
#include <hip/hip_bf16.h>

#define NN 50000
#define NE 800000

// ---------------- degree / norm ----------------
__global__ void deg_kernel(const int* __restrict__ dst, float* __restrict__ deg, int nE) {
    int e = blockIdx.x * blockDim.x + threadIdx.x;
    if (e < nE) atomicAdd(&deg[dst[e]], 1.0f);
}

__global__ void dinv_kernel(float* __restrict__ deg, int n) {
    int i = blockIdx.x * blockDim.x + threadIdx.x;
    if (i < n) deg[i] = 1.0f / sqrtf(deg[i] + 1.0f);
}

// ---------------- scatter-add of 128-dim features with edge norm ----------------
// one 64-lane wave per edge; each lane covers dims {lane, lane+64}
__global__ void scatter128_kernel(const float* __restrict__ feat,
                                  const int* __restrict__ src,
                                  const int* __restrict__ dst,
                                  const float* __restrict__ dinv,
                                  float* __restrict__ agg, int nE) {
    int e = blockIdx.x * (blockDim.x >> 6) + (threadIdx.x >> 6);
    int lane = threadIdx.x & 63;
    if (e >= nE) return;
    int s = src[e], d = dst[e];
    float coef = dinv[s] * dinv[d];
    const float* fr = feat + (size_t)s * 128;
    float* ar = agg + (size_t)d * 128;
    atomicAdd(&ar[lane],      fr[lane]      * coef);
    atomicAdd(&ar[lane + 64], fr[lane + 64] * coef);
}

// ---------------- conv1: h = relu((aggx + x*dinv^2) @ W1 + b1), out 256 ----------------
__global__ void gemm1_kernel(const float* __restrict__ aggx, const float* __restrict__ x,
                             const float* __restrict__ dinv, const float* __restrict__ W1,
                             const float* __restrict__ b1, float* __restrict__ h, int n) {
    __shared__ float r[128];
    int node = blockIdx.x;
    int t = threadIdx.x; // 256
    if (node >= n) return;
    if (t < 128) {
        float s = dinv[node];
        r[t] = aggx[(size_t)node * 128 + t] + x[(size_t)node * 128 + t] * (s * s);
    }
    __syncthreads();
    float acc = b1[t];
#pragma unroll
    for (int k = 0; k < 128; ++k) acc += r[k] * W1[k * 256 + t];
    h[(size_t)node * 256 + t] = fmaxf(acc, 0.0f);
}

// ---------------- conv2 pre-matmul: h2pre = h @ W2, out 128 ----------------
__global__ void gemm2_kernel(const float* __restrict__ h, const float* __restrict__ W2,
                             float* __restrict__ h2pre, int n) {
    __shared__ float r[256];
    int node = blockIdx.x;
    int t = threadIdx.x; // 128
    if (node >= n) return;
    r[t]       = h[(size_t)node * 256 + t];
    r[t + 128] = h[(size_t)node * 256 + t + 128];
    __syncthreads();
    float acc = 0.0f;
#pragma unroll
    for (int k = 0; k < 256; ++k) acc += r[k] * W2[k * 128 + t];
    h2pre[(size_t)node * 128 + t] = acc;
}

// ---------------- conv2 epilogue: h2 = relu(agg2 + h2pre*dinv^2 + b2) ----------------
__global__ void node2_kernel(const float* __restrict__ agg2, const float* __restrict__ h2pre,
                             const float* __restrict__ dinv, const float* __restrict__ b2,
                             float* __restrict__ h2, int n) {
    int i = blockIdx.x * blockDim.x + threadIdx.x;
    if (i >= n * 128) return;
    int node = i >> 7, d = i & 127;
    float s = dinv[node];
    h2[i] = fmaxf(agg2[i] + h2pre[i] * s * s + b2[d], 0.0f);
}

// ---------------- global mean partial sums ----------------
__global__ void gsum_kernel(const float* __restrict__ h2, float* __restrict__ gsum, int n) {
    int t = threadIdx.x; // 128 = dim
    float acc = 0.0f;
    for (int node = blockIdx.x; node < n; node += gridDim.x)
        acc += h2[(size_t)node * 128 + t];
    atomicAdd(&gsum[t], acc);
}

// ---------------- heads on pooled vector (single block, 256 threads) ----------------
__global__ void head_kernel(const float* __restrict__ gsum,
                            const float* __restrict__ fc1W, const float* __restrict__ fc1b,
                            const float* __restrict__ fc2W, const float* __restrict__ fc2b,
                            const float* __restrict__ gpW, const float* __restrict__ gpb,
                            float* __restrict__ out_gl, float* __restrict__ out_val, int n) {
    __shared__ float g[128];
    __shared__ float red[256];
    int t = threadIdx.x;
    if (t < 128) g[t] = gsum[t] * (1.0f / (float)n);
    __syncthreads();
    float v = fc1b[t];
#pragma unroll
    for (int k = 0; k < 128; ++k) v += g[k] * fc1W[k * 256 + t];
    v = fmaxf(v, 0.0f);
    red[t] = v * fc2W[t];
    __syncthreads();
    for (int s = 128; s > 0; s >>= 1) { if (t < s) red[t] += red[t + s]; __syncthreads(); }
    if (t == 0) out_val[0] = red[0] + fc2b[0];
    __syncthreads();
    red[t] = (t < 128) ? g[t] * gpW[t] : 0.0f;
    __syncthreads();
    for (int s = 128; s > 0; s >>= 1) { if (t < s) red[t] += red[t + s]; __syncthreads(); }
    if (t == 0) out_gl[0] = red[0] + gpb[0];
}

// ---------------- node logits: [N,3] = h2 @ npW + npb ----------------
__global__ void nodelogits_kernel(const float* __restrict__ h2, const float* __restrict__ npW,
                                  const float* __restrict__ npb, float* __restrict__ out, int n) {
    int node = blockIdx.x * (blockDim.x >> 6) + (threadIdx.x >> 6);
    int lane = threadIdx.x & 63;
    if (node >= n) return;
    float v0 = h2[(size_t)node * 128 + lane];
    float v1 = h2[(size_t)node * 128 + 64 + lane];
    float c0 = v0 * npW[lane * 3 + 0] + v1 * npW[(lane + 64) * 3 + 0];
    float c1 = v0 * npW[lane * 3 + 1] + v1 * npW[(lane + 64) * 3 + 1];
    float c2 = v0 * npW[lane * 3 + 2] + v1 * npW[(lane + 64) * 3 + 2];
    for (int off = 32; off; off >>= 1) {
        c0 += __shfl_down(c0, off);
        c1 += __shfl_down(c1, off);
        c2 += __shfl_down(c2, off);
    }
    if (lane == 0) {
        out[(size_t)node * 3 + 0] = c0 + npb[0];
        out[(size_t)node * 3 + 1] = c1 + npb[1];
        out[(size_t)node * 3 + 2] = c2 + npb[2];
    }
}

// ---------------- edge logits: [E,2] from concat(h2[src], h2[dst]) @ epW + epb ----------------
__global__ void edgelogits_kernel(const float* __restrict__ h2, const int* __restrict__ src,
                                  const int* __restrict__ dst, const float* __restrict__ epW,
                                  const float* __restrict__ epb, float* __restrict__ out, int nE) {
    int e = blockIdx.x * (blockDim.x >> 6) + (threadIdx.x >> 6);
    int lane = threadIdx.x & 63;
    if (e >= nE) return;
    int s = src[e], d = dst[e];
    float a0 = h2[(size_t)s * 128 + lane];
    float a1 = h2[(size_t)s * 128 + 64 + lane];
    float b0 = h2[(size_t)d * 128 + lane];
    float b1 = h2[(size_t)d * 128 + 64 + lane];
    float c0 = a0 * epW[lane * 2 + 0] + a1 * epW[(lane + 64) * 2 + 0]
             + b0 * epW[(lane + 128) * 2 + 0] + b1 * epW[(lane + 192) * 2 + 0];
    float c1 = a0 * epW[lane * 2 + 1] + a1 * epW[(lane + 64) * 2 + 1]
             + b0 * epW[(lane + 128) * 2 + 1] + b1 * epW[(lane + 192) * 2 + 1];
    for (int off = 32; off; off >>= 1) {
        c0 += __shfl_down(c0, off);
        c1 += __shfl_down(c1, off);
    }
    if (lane == 0) {
        out[(size_t)e * 2 + 0] = c0 + epb[0];
        out[(size_t)e * 2 + 1] = c1 + epb[1];
    }
}

extern "C" void kernel_launch(void* const* d_in, const int* in_sizes, int n_in,
                              void* d_out, int out_size, void* d_ws, size_t ws_size,
                              hipStream_t stream) {
    const float* x    = (const float*)d_in[0];
    const int*   ei   = (const int*)d_in[1];
    const float* W1   = (const float*)d_in[2];
    const float* b1   = (const float*)d_in[3];
    const float* W2   = (const float*)d_in[4];
    const float* b2   = (const float*)d_in[5];
    const float* fc1W = (const float*)d_in[6];
    const float* fc1b = (const float*)d_in[7];
    const float* fc2W = (const float*)d_in[8];
    const float* fc2b = (const float*)d_in[9];
    const float* npW  = (const float*)d_in[10];
    const float* npb  = (const float*)d_in[11];
    const float* epW  = (const float*)d_in[12];
    const float* epb  = (const float*)d_in[13];
    const float* gpW  = (const float*)d_in[14];
    const float* gpb  = (const float*)d_in[15];
    float* out = (float*)d_out;

    const int n = in_sizes[0] / 128;       // 50000
    const int E = in_sizes[1] / 2;         // 800000
    const int* src = ei;
    const int* dst = ei + E;

    // workspace layout (floats)
    float* ws = (float*)d_ws;
    float* bufA = ws;                       // 12.8M floats: aggx[0:6.4M] -> h2pre[0:6.4M], agg2[6.4M:12.8M]
    float* bufB = ws + (size_t)n * 256;     // 12.8M floats: h -> h2[0:6.4M]
    float* dinv = bufB + (size_t)n * 256;   // n floats (deg then dinv in place)
    float* gsum = dinv + n;                 // 128 floats

    float* aggx  = bufA;
    float* h2pre = bufA;
    float* agg2  = bufA + (size_t)n * 128;
    float* h     = bufB;
    float* h2    = bufB;

    // output layout
    float* out_nl  = out;                         // [n,3]
    float* out_el  = out + (size_t)n * 3;         // [E,2]
    float* out_gl  = out + (size_t)n * 3 + (size_t)E * 2;
    float* out_val = out_gl + 1;

    // zero: bufA (aggx + agg2), deg, gsum
    hipMemsetAsync(bufA, 0, (size_t)n * 256 * sizeof(float), stream);
    hipMemsetAsync(dinv, 0, (size_t)(n + 128) * sizeof(float), stream);

    deg_kernel<<<(E + 255) / 256, 256, 0, stream>>>(dst, dinv, E);
    dinv_kernel<<<(n + 255) / 256, 256, 0, stream>>>(dinv, n);

    // conv1: aggregate x (128 dims), then fused matmul+bias+relu -> h [n,256]
    scatter128_kernel<<<(E + 3) / 4, 256, 0, stream>>>(x, src, dst, dinv, aggx, E);
    gemm1_kernel<<<n, 256, 0, stream>>>(aggx, x, dinv, W1, b1, h, n);

    // conv2: matmul first (256->128), then aggregate, then epilogue
    gemm2_kernel<<<n, 128, 0, stream>>>(h, W2, h2pre, n);
    scatter128_kernel<<<(E + 3) / 4, 256, 0, stream>>>(h2pre, src, dst, dinv, agg2, E);
    node2_kernel<<<(n * 128 + 255) / 256, 256, 0, stream>>>(agg2, h2pre, dinv, b2, h2, n);

    // pooled heads
    gsum_kernel<<<256, 128, 0, stream>>>(h2, gsum, n);
    head_kernel<<<1, 256, 0, stream>>>(gsum, fc1W, fc1b, fc2W, fc2b, gpW, gpb, out_gl, out_val, n);

    // node + edge logits
    nodelogits_kernel<<<(n + 3) / 4, 256, 0, stream>>>(h2, npW, npb, out_nl, n);
    edgelogits_kernel<<<(E + 3) / 4, 256, 0, stream>>>(h2, src, dst, epW, epb, out_el, E);
}

// Round 3
// 510.031 us; speedup vs baseline: 2.7980x; 2.7980x over previous
//
#include <hip/hip_runtime.h>
#include <hip/hip_bf16.h>

// ---------------- degree histogram (int) ----------------
__global__ void hist_kernel(const int* __restrict__ dst, int* __restrict__ deg, int nE) {
    int e = blockIdx.x * blockDim.x + threadIdx.x;
    if (e < nE) atomicAdd(&deg[dst[e]], 1);
}

// ---------------- dinv = rsqrt(deg+1) ----------------
__global__ void dinv_kernel(const int* __restrict__ deg, float* __restrict__ dinv, int n) {
    int i = blockIdx.x * blockDim.x + threadIdx.x;
    if (i < n) dinv[i] = rsqrtf((float)(deg[i] + 1));
}

// ---------------- exclusive scan of deg -> start (single block, 1024 thr) ----------------
__global__ __launch_bounds__(1024) void scan_kernel(const int* __restrict__ deg,
                                                    int* __restrict__ start, int n) {
    __shared__ int wsum[16];
    __shared__ int woff[16];
    __shared__ int carry_s;
    __shared__ int tot_s;
    int t = threadIdx.x, lane = t & 63, wid = t >> 6;
    if (t == 0) carry_s = 0;
    __syncthreads();
    for (int base = 0; base < n; base += 1024) {
        int i = base + t;
        int val = (i < n) ? deg[i] : 0;
        int inc = val;
        for (int s = 1; s < 64; s <<= 1) {
            int tmp = __shfl_up(inc, s);
            if (lane >= s) inc += tmp;
        }
        if (lane == 63) wsum[wid] = inc;
        __syncthreads();
        if (wid == 0) {
            int w = (lane < 16) ? wsum[lane] : 0;
            for (int s = 1; s < 16; s <<= 1) {
                int tmp = __shfl_up(w, s);
                if (lane >= s) w += tmp;
            }
            if (lane < 16) woff[lane] = w - wsum[lane];
            if (lane == 15) tot_s = w;
        }
        __syncthreads();
        if (i < n) start[i] = carry_s + woff[wid] + (inc - val);
        __syncthreads();
        if (t == 0) carry_s += tot_s;
        // next-iteration barriers order carry_s update before any read
    }
}

// ---------------- CSR fill: csr[pos] = (src, coef) ----------------
__global__ void fill_kernel(const int* __restrict__ src, const int* __restrict__ dst,
                            const int* __restrict__ start, int* __restrict__ cnt,
                            const float* __restrict__ dinv, int2* __restrict__ csr, int nE) {
    int e = blockIdx.x * blockDim.x + threadIdx.x;
    if (e >= nE) return;
    int s = src[e], d = dst[e];
    int pos = start[d] + atomicAdd(&cnt[d], 1);
    float w = dinv[s] * dinv[d];
    csr[pos] = make_int2(s, __float_as_int(w));
}

// ---------------- conv1 gather: xin = sum coef*x[src] + dinv^2 * x ----------------
__global__ __launch_bounds__(256) void gather1_kernel(const float* __restrict__ x,
                                                      const int2* __restrict__ csr,
                                                      const int* __restrict__ start,
                                                      const int* __restrict__ deg,
                                                      const float* __restrict__ dinv,
                                                      float* __restrict__ xin, int n) {
    int node = blockIdx.x * 4 + (threadIdx.x >> 6);
    int lane = threadIdx.x & 63;
    if (node >= n) return;
    int p = start[node];
    int e0 = p + deg[node];
    float a0 = 0.f, a1 = 0.f;
    for (; p + 1 < e0; p += 2) {
        int2 c0 = csr[p], c1 = csr[p + 1];
        float w0 = __int_as_float(c0.y), w1 = __int_as_float(c1.y);
        const float* r0 = x + (size_t)c0.x * 128;
        const float* r1 = x + (size_t)c1.x * 128;
        a0 += w0 * r0[lane];
        a1 += w0 * r0[lane + 64];
        a0 += w1 * r1[lane];
        a1 += w1 * r1[lane + 64];
    }
    if (p < e0) {
        int2 c0 = csr[p];
        float w0 = __int_as_float(c0.y);
        const float* r0 = x + (size_t)c0.x * 128;
        a0 += w0 * r0[lane];
        a1 += w0 * r0[lane + 64];
    }
    float di = dinv[node];
    float d2 = di * di;
    const float* xr = x + (size_t)node * 128;
    a0 += d2 * xr[lane];
    a1 += d2 * xr[lane + 64];
    xin[(size_t)node * 128 + lane] = a0;
    xin[(size_t)node * 128 + 64 + lane] = a1;
}

// ---------------- tiled f32 GEMM: out[n,NOUT] = A[n,K] @ W[K,NOUT] (+bias, relu) ----------------
template <int K, int NOUT, bool BIAS_RELU>
__global__ __launch_bounds__(256) void gemm_kernel(const float* __restrict__ A,
                                                   const float* __restrict__ W,
                                                   const float* __restrict__ bias,
                                                   float* __restrict__ out, int n) {
    __shared__ __align__(16) float Ast[32][72];  // transposed A tile, padded
    __shared__ __align__(16) float Ws[32][64];
    int m0 = blockIdx.x * 64;
    int j0 = blockIdx.y * 64;
    int t = threadIdx.x;
    int tx = t & 15, ty = t >> 4;
    float acc[4][4] = {{0.f}};
    for (int kk = 0; kk < K; kk += 32) {
#pragma unroll
        for (int l = 0; l < 2; ++l) {
            int f = t * 2 + l;       // 0..511
            int row = f >> 3;        // 64 rows
            int c4 = f & 7;          // 8 float4 per row
            float4 av = make_float4(0.f, 0.f, 0.f, 0.f);
            int grow = m0 + row;
            if (grow < n) av = *(const float4*)&A[(size_t)grow * K + kk + c4 * 4];
            Ast[c4 * 4 + 0][row] = av.x;
            Ast[c4 * 4 + 1][row] = av.y;
            Ast[c4 * 4 + 2][row] = av.z;
            Ast[c4 * 4 + 3][row] = av.w;
        }
#pragma unroll
        for (int l = 0; l < 2; ++l) {
            int f = t * 2 + l;
            int row = f >> 4;        // 32 rows
            int c4 = f & 15;         // 16 float4 per row
            *(float4*)&Ws[row][c4 * 4] =
                *(const float4*)&W[(size_t)(kk + row) * NOUT + j0 + c4 * 4];
        }
        __syncthreads();
#pragma unroll
        for (int k = 0; k < 32; ++k) {
            float4 a = *(const float4*)&Ast[k][ty * 4];
            float4 b = *(const float4*)&Ws[k][tx * 4];
            float ar[4] = {a.x, a.y, a.z, a.w};
            float br[4] = {b.x, b.y, b.z, b.w};
#pragma unroll
            for (int i = 0; i < 4; ++i)
#pragma unroll
                for (int j = 0; j < 4; ++j) acc[i][j] += ar[i] * br[j];
        }
        __syncthreads();
    }
#pragma unroll
    for (int i = 0; i < 4; ++i) {
        int grow = m0 + ty * 4 + i;
        if (grow >= n) continue;
        float4 o;
        if (BIAS_RELU) {
            o.x = fmaxf(acc[i][0] + bias[j0 + tx * 4 + 0], 0.f);
            o.y = fmaxf(acc[i][1] + bias[j0 + tx * 4 + 1], 0.f);
            o.z = fmaxf(acc[i][2] + bias[j0 + tx * 4 + 2], 0.f);
            o.w = fmaxf(acc[i][3] + bias[j0 + tx * 4 + 3], 0.f);
        } else {
            o.x = acc[i][0]; o.y = acc[i][1]; o.z = acc[i][2]; o.w = acc[i][3];
        }
        *(float4*)&out[(size_t)grow * NOUT + j0 + tx * 4] = o;
    }
}

// ---------------- conv2 gather + epilogue + node logits + edge partials + gsum ----------------
__global__ __launch_bounds__(256) void conv2_fused_kernel(
    const float* __restrict__ h2pre, const int2* __restrict__ csr,
    const int* __restrict__ start, const int* __restrict__ deg,
    const float* __restrict__ dinv, const float* __restrict__ b2,
    const float* __restrict__ npW, const float* __restrict__ npb,
    const float* __restrict__ epW, const float* __restrict__ epb,
    float* __restrict__ out_nl, float* __restrict__ uv,
    float* __restrict__ gsum, int n) {
    __shared__ float lgs[4][128];
    int lane = threadIdx.x & 63;
    int wid = threadIdx.x >> 6;
    lgs[wid][lane] = 0.f;
    lgs[wid][lane + 64] = 0.f;
    // hoisted per-lane weights (node-independent)
    float wn0l = npW[lane * 3 + 0], wn1l = npW[lane * 3 + 1], wn2l = npW[lane * 3 + 2];
    float wn0h = npW[(lane + 64) * 3 + 0], wn1h = npW[(lane + 64) * 3 + 1], wn2h = npW[(lane + 64) * 3 + 2];
    float wu0l = epW[lane * 2 + 0], wu1l = epW[lane * 2 + 1];
    float wu0h = epW[(lane + 64) * 2 + 0], wu1h = epW[(lane + 64) * 2 + 1];
    float wv0l = epW[(lane + 128) * 2 + 0], wv1l = epW[(lane + 128) * 2 + 1];
    float wv0h = epW[(lane + 192) * 2 + 0], wv1h = epW[(lane + 192) * 2 + 1];
    float b2l = b2[lane], b2h = b2[lane + 64];
    float npb0 = npb[0], npb1 = npb[1], npb2 = npb[2];
    float epb0 = epb[0], epb1 = epb[1];

    for (int node = blockIdx.x * 4 + wid; node < n; node += gridDim.x * 4) {
        int p = start[node];
        int e0 = p + deg[node];
        float a0 = 0.f, a1 = 0.f;
        for (; p + 1 < e0; p += 2) {
            int2 c0 = csr[p], c1 = csr[p + 1];
            float w0 = __int_as_float(c0.y), w1 = __int_as_float(c1.y);
            const float* r0 = h2pre + (size_t)c0.x * 128;
            const float* r1 = h2pre + (size_t)c1.x * 128;
            a0 += w0 * r0[lane];
            a1 += w0 * r0[lane + 64];
            a0 += w1 * r1[lane];
            a1 += w1 * r1[lane + 64];
        }
        if (p < e0) {
            int2 c0 = csr[p];
            float w0 = __int_as_float(c0.y);
            const float* r0 = h2pre + (size_t)c0.x * 128;
            a0 += w0 * r0[lane];
            a1 += w0 * r0[lane + 64];
        }
        float di = dinv[node];
        float d2 = di * di;
        const float* sr = h2pre + (size_t)node * 128;
        a0 = fmaxf(a0 + d2 * sr[lane] + b2l, 0.f);
        a1 = fmaxf(a1 + d2 * sr[lane + 64] + b2h, 0.f);
        // pool accumulation
        lgs[wid][lane] += a0;
        lgs[wid][lane + 64] += a1;
        // 7 dot products, wave-reduced
        float n0 = a0 * wn0l + a1 * wn0h;
        float n1 = a0 * wn1l + a1 * wn1h;
        float n2 = a0 * wn2l + a1 * wn2h;
        float u0 = a0 * wu0l + a1 * wu0h;
        float u1 = a0 * wu1l + a1 * wu1h;
        float v0 = a0 * wv0l + a1 * wv0h;
        float v1 = a0 * wv1l + a1 * wv1h;
        for (int off = 32; off; off >>= 1) {
            n0 += __shfl_xor(n0, off);
            n1 += __shfl_xor(n1, off);
            n2 += __shfl_xor(n2, off);
            u0 += __shfl_xor(u0, off);
            u1 += __shfl_xor(u1, off);
            v0 += __shfl_xor(v0, off);
            v1 += __shfl_xor(v1, off);
        }
        if (lane == 0) {
            out_nl[(size_t)node * 3 + 0] = n0 + npb0;
            out_nl[(size_t)node * 3 + 1] = n1 + npb1;
            out_nl[(size_t)node * 3 + 2] = n2 + npb2;
            float4 o;
            o.x = u0 + epb0; o.y = u1 + epb1; o.z = v0; o.w = v1;
            *(float4*)&uv[(size_t)node * 4] = o;
        }
    }
    __syncthreads();
    int t = threadIdx.x;
    if (t < 128) {
        float tot = lgs[0][t] + lgs[1][t] + lgs[2][t] + lgs[3][t];
        atomicAdd(&gsum[t], tot);
    }
}

// ---------------- heads on pooled vector ----------------
__global__ void head_kernel(const float* __restrict__ gsum,
                            const float* __restrict__ fc1W, const float* __restrict__ fc1b,
                            const float* __restrict__ fc2W, const float* __restrict__ fc2b,
                            const float* __restrict__ gpW, const float* __restrict__ gpb,
                            float* __restrict__ out_gl, float* __restrict__ out_val, int n) {
    __shared__ float g[128];
    __shared__ float red[256];
    int t = threadIdx.x;
    if (t < 128) g[t] = gsum[t] * (1.0f / (float)n);
    __syncthreads();
    float v = fc1b[t];
#pragma unroll
    for (int k = 0; k < 128; ++k) v += g[k] * fc1W[k * 256 + t];
    v = fmaxf(v, 0.0f);
    red[t] = v * fc2W[t];
    __syncthreads();
    for (int s = 128; s > 0; s >>= 1) { if (t < s) red[t] += red[t + s]; __syncthreads(); }
    if (t == 0) out_val[0] = red[0] + fc2b[0];
    __syncthreads();
    red[t] = (t < 128) ? g[t] * gpW[t] : 0.0f;
    __syncthreads();
    for (int s = 128; s > 0; s >>= 1) { if (t < s) red[t] += red[t + s]; __syncthreads(); }
    if (t == 0) out_gl[0] = red[0] + gpb[0];
}

// ---------------- edge logits from per-node partials ----------------
__global__ void edge_kernel(const float* __restrict__ uv, const int* __restrict__ src,
                            const int* __restrict__ dst, float* __restrict__ out, int nE) {
    int e = blockIdx.x * blockDim.x + threadIdx.x;
    if (e >= nE) return;
    int s = src[e], d = dst[e];
    float2 u = *(const float2*)&uv[(size_t)s * 4];
    float2 v = *(const float2*)&uv[(size_t)d * 4 + 2];
    float2 o; o.x = u.x + v.x; o.y = u.y + v.y;
    *(float2*)&out[(size_t)e * 2] = o;
}

extern "C" void kernel_launch(void* const* d_in, const int* in_sizes, int n_in,
                              void* d_out, int out_size, void* d_ws, size_t ws_size,
                              hipStream_t stream) {
    const float* x    = (const float*)d_in[0];
    const int*   ei   = (const int*)d_in[1];
    const float* W1   = (const float*)d_in[2];
    const float* b1   = (const float*)d_in[3];
    const float* W2   = (const float*)d_in[4];
    const float* b2   = (const float*)d_in[5];
    const float* fc1W = (const float*)d_in[6];
    const float* fc1b = (const float*)d_in[7];
    const float* fc2W = (const float*)d_in[8];
    const float* fc2b = (const float*)d_in[9];
    const float* npW  = (const float*)d_in[10];
    const float* npb  = (const float*)d_in[11];
    const float* epW  = (const float*)d_in[12];
    const float* epb  = (const float*)d_in[13];
    const float* gpW  = (const float*)d_in[14];
    const float* gpb  = (const float*)d_in[15];
    float* out = (float*)d_out;

    const int n = in_sizes[0] / 128;   // 50000
    const int E = in_sizes[1] / 2;     // 800000
    const int* src = ei;
    const int* dst = ei + E;

    // workspace layout
    float* ws    = (float*)d_ws;
    float* h     = ws;                             // [n,256]
    float* xin   = h + (size_t)n * 256;            // [n,128]; reused as h2pre
    float* h2pre = xin;
    int2*  csr   = (int2*)(xin + (size_t)n * 128); // [E] (src, coef)
    int*   deg   = (int*)(csr + E);                // [n]
    int*   startp= deg + n;                        // [n]
    int*   cnt   = startp + n;                     // [n]
    float* dinv  = (float*)(cnt + n);              // [n]
    float* uv    = dinv + n;                       // [n,4]
    float* gsum  = uv + (size_t)n * 4;             // [128]

    // output layout
    float* out_nl  = out;                          // [n,3]
    float* out_el  = out + (size_t)n * 3;          // [E,2]
    float* out_gl  = out + (size_t)n * 3 + (size_t)E * 2;
    float* out_val = out_gl + 1;

    hipMemsetAsync(deg, 0, (size_t)3 * n * sizeof(int), stream);   // deg,start,cnt
    hipMemsetAsync(gsum, 0, 128 * sizeof(float), stream);

    hist_kernel<<<(E + 255) / 256, 256, 0, stream>>>(dst, deg, E);
    dinv_kernel<<<(n + 255) / 256, 256, 0, stream>>>(deg, dinv, n);
    scan_kernel<<<1, 1024, 0, stream>>>(deg, startp, n);
    fill_kernel<<<(E + 255) / 256, 256, 0, stream>>>(src, dst, startp, cnt, dinv, csr, E);

    gather1_kernel<<<(n + 3) / 4, 256, 0, stream>>>(x, csr, startp, deg, dinv, xin, n);

    dim3 g1((n + 63) / 64, 256 / 64);
    gemm_kernel<128, 256, true><<<g1, 256, 0, stream>>>(xin, W1, b1, h, n);
    dim3 g2((n + 63) / 64, 128 / 64);
    gemm_kernel<256, 128, false><<<g2, 256, 0, stream>>>(h, W2, nullptr, h2pre, n);

    conv2_fused_kernel<<<1024, 256, 0, stream>>>(h2pre, csr, startp, deg, dinv, b2,
                                                 npW, npb, epW, epb, out_nl, uv, gsum, n);

    head_kernel<<<1, 256, 0, stream>>>(gsum, fc1W, fc1b, fc2W, fc2b, gpW, gpb, out_gl, out_val, n);
    edge_kernel<<<(E + 255) / 256, 256, 0, stream>>>(uv, src, dst, out_el, E);
}